// Round 8
// baseline (489.749 us; speedup 1.0000x reference)
//
#include <hip/hip_runtime.h>

// SigmoidDVHLoss: per-(batch,label) mean of sigmoid((dose-thr)/0.1) for pred
// and target, then MSE over the 8x3 DVH entries.
//
// loss = mean_{b,k} ( (sum_{m==k}(sig_p - sig_t)) / count_k )^2
//
// R5 (confirmed): global f64 hot-line atomics were the ~70us pacer ->
//   per-block partials + separate reduce = 41.5us.
// R6: staged vmcnt waits neutral -> steady state is paced by the shared
//   XCD<->L3 stream rate (~5.5 TB/s effective); intra-wave scheduling
//   doesn't matter. VALU work ~6us of ~36us; bytes irreducible.
// R7: reclaim the epilogue overhead (2nd launch + gap + serial finalize):
//   last-block-reduces pattern. Partial stores -> __threadfence (device
//   release) -> atomicAdd on one counter (once per block, 4096 total,
//   spread in time) -> last block __threadfence (acquire) + reduces all
//   partials + writes the scalar. Counter zeroed per call via memset.

#define NB 8
#define NK 3
#define VPB (1 << 21)        // 128^3 voxels per batch
#define BLOCK 256
#define CHUNKS 512           // blocks per batch
#define NBLOCKS (NB * CHUNKS)            // 4096
#define VOX_PER_BLOCK (VPB / CHUNKS)     // 4096 voxels = 1024 float4

#define LOG2E_X10 14.4269504088896341f   // 10 / ln(2)

typedef float v4f __attribute__((ext_vector_type(4)));
typedef int   v4i __attribute__((ext_vector_type(4)));

// ws layout: int counter (zeroed per call) | pad to 256B |
//            float diff[3][NBLOCKS] | int count[3][NBLOCKS]

__global__ __launch_bounds__(BLOCK) void dvh_kernel(
    const float* __restrict__ pred,
    const float* __restrict__ targ,
    const int*   __restrict__ mask,
    const float* __restrict__ ptv,
    float*       __restrict__ wsd,
    int*         __restrict__ wsc,
    int*         __restrict__ counter,
    float*       __restrict__ out)
{
    const int bid   = blockIdx.x;
    const int batch = bid / CHUNKS;
    const int chunk = bid % CHUNKS;
    const long base = (long)batch * VPB + (long)chunk * VOX_PER_BLOCK;

    const float* predb = pred + base;   // uniform -> SGPR pair
    const float* targb = targ + base;
    const int*   maskb = mask + base;

    const int tid = threadIdx.x;
    const unsigned off0 = (unsigned)(tid) * 16u;
    const unsigned off1 = (unsigned)(tid + BLOCK) * 16u;
    const unsigned off2 = (unsigned)(tid + 2 * BLOCK) * 16u;
    const unsigned off3 = (unsigned)(tid + 3 * BLOCK) * 16u;

    v4f P0, P1, P2, P3, T0, T1, T2, T3;
    v4i M0, M1, M2, M3;

    // all 12 loads issued back-to-back, one wait (R5 form, benched best)
    asm volatile(
        "global_load_dwordx4 %0,  %12, %16\n\t"
        "global_load_dwordx4 %1,  %13, %16\n\t"
        "global_load_dwordx4 %2,  %14, %16\n\t"
        "global_load_dwordx4 %3,  %15, %16\n\t"
        "global_load_dwordx4 %4,  %12, %17\n\t"
        "global_load_dwordx4 %5,  %13, %17\n\t"
        "global_load_dwordx4 %6,  %14, %17\n\t"
        "global_load_dwordx4 %7,  %15, %17\n\t"
        "global_load_dwordx4 %8,  %12, %18\n\t"
        "global_load_dwordx4 %9,  %13, %18\n\t"
        "global_load_dwordx4 %10, %14, %18\n\t"
        "global_load_dwordx4 %11, %15, %18\n\t"
        "s_waitcnt vmcnt(0)"
        : "=&v"(P0), "=&v"(P1), "=&v"(P2), "=&v"(P3),
          "=&v"(T0), "=&v"(T1), "=&v"(T2), "=&v"(T3),
          "=&v"(M0), "=&v"(M1), "=&v"(M2), "=&v"(M3)
        : "v"(off0), "v"(off1), "v"(off2), "v"(off3),
          "s"(predb), "s"(targb), "s"(maskb));

    // scaled thresholds: sig = rcp(1 + 2^(thr*C - d*C))
    const float tc0 = ptv[0] * LOG2E_X10;
    const float tc1 = ptv[1] * LOG2E_X10;
    const float tc2 = ptv[2] * LOG2E_X10;

    float d0 = 0.f, d1 = 0.f, d2 = 0.f;   // sum of (sig_p - sig_t) per label
    int   c0 = 0,   c1 = 0,   c2 = 0;     // counts per label

    #define DO_ELEM(PJ, TJ, MJ)                                          \
    {                                                                    \
        const int mm = (MJ);                                             \
        const bool is1 = (mm == 1), is2 = (mm == 2), is3 = (mm == 3);    \
        const float thrC = is1 ? tc0 : (is2 ? tc1 : tc2);                \
        const float ep = __builtin_amdgcn_exp2f(                         \
                             __builtin_fmaf((PJ), -LOG2E_X10, thrC));    \
        const float et = __builtin_amdgcn_exp2f(                         \
                             __builtin_fmaf((TJ), -LOG2E_X10, thrC));    \
        const float sgp = __builtin_amdgcn_rcpf(1.0f + ep);              \
        const float sgt = __builtin_amdgcn_rcpf(1.0f + et);              \
        const float df  = sgp - sgt;                                     \
        d0 += is1 ? df : 0.0f;                                           \
        d1 += is2 ? df : 0.0f;                                           \
        d2 += is3 ? df : 0.0f;                                           \
        c0 += is1 ? 1 : 0;                                               \
        c1 += is2 ? 1 : 0;                                               \
        c2 += is3 ? 1 : 0;                                               \
    }

    #define DO_VEC4(P, T, M)                                             \
        DO_ELEM(P[0], T[0], M[0])                                        \
        DO_ELEM(P[1], T[1], M[1])                                        \
        DO_ELEM(P[2], T[2], M[2])                                        \
        DO_ELEM(P[3], T[3], M[3])

    DO_VEC4(P0, T0, M0)
    DO_VEC4(P1, T1, M1)
    DO_VEC4(P2, T2, M2)
    DO_VEC4(P3, T3, M3)
    #undef DO_VEC4
    #undef DO_ELEM

    // wave(64) butterfly reduce: f32 for diffs, int for counts
    #pragma unroll
    for (int off = 32; off > 0; off >>= 1) {
        d0 += __shfl_down(d0, off, 64);
        d1 += __shfl_down(d1, off, 64);
        d2 += __shfl_down(d2, off, 64);
        c0 += __shfl_down(c0, off, 64);
        c1 += __shfl_down(c1, off, 64);
        c2 += __shfl_down(c2, off, 64);
    }

    __shared__ float redd[BLOCK / 64][3];
    __shared__ int   redc[BLOCK / 64][3];
    const int wid  = threadIdx.x >> 6;
    const int lane = threadIdx.x & 63;
    if (lane == 0) {
        redd[wid][0] = d0; redd[wid][1] = d1; redd[wid][2] = d2;
        redc[wid][0] = c0; redc[wid][1] = c1; redc[wid][2] = c2;
    }
    __syncthreads();

    if (tid < 6) {
        const int q = tid;                   // 0..2 diff, 3..5 count
        if (q < 3)
            wsd[(size_t)q * NBLOCKS + bid] =
                redd[0][q] + redd[1][q] + redd[2][q] + redd[3][q];
        else
            wsc[(size_t)(q - 3) * NBLOCKS + bid] =
                redc[0][q - 3] + redc[1][q - 3] + redc[2][q - 3] + redc[3][q - 3];
    }

    // ---- last-block-reduces epilogue (device-scope fences, Guideline 16) ----
    __syncthreads();          // all partial stores issued block-wide
    __threadfence();          // device-scope release of partial stores
    __shared__ int is_last;
    if (tid == 0)
        is_last = (atomicAdd(counter, 1) == NBLOCKS - 1);
    __syncthreads();
    if (!is_last) return;

    __threadfence();          // device-scope acquire before reading partials

    __shared__ double lds24[NB * NK];
    for (int j = wid; j < NB * NK; j += BLOCK / 64) {   // 6 pairs per wave
        const int b = j / NK, k = j % NK;
        const float* dp = wsd + (size_t)k * NBLOCKS + b * CHUNKS;
        const int*   cp = wsc + (size_t)k * NBLOCKS + b * CHUNKS;

        double sd = 0.0;
        int    sc = 0;
        #pragma unroll
        for (int i = lane; i < CHUNKS; i += 64) {       // 8 elems each
            sd += (double)dp[i];
            sc += cp[i];
        }
        #pragma unroll
        for (int off = 32; off > 0; off >>= 1) {
            sd += __shfl_down(sd, off, 64);
            sc += __shfl_down(sc, off, 64);
        }
        if (lane == 0) {
            const double d = sd / (double)sc;
            lds24[j] = d * d;
        }
    }
    __syncthreads();

    if (tid == 0) {
        double t = 0.0;
        #pragma unroll
        for (int j = 0; j < NB * NK; ++j) t += lds24[j];
        out[0] = (float)(t / (double)(NB * NK));
    }
}

extern "C" void kernel_launch(void* const* d_in, const int* in_sizes, int n_in,
                              void* d_out, int out_size, void* d_ws, size_t ws_size,
                              hipStream_t stream) {
    const float* pred = (const float*)d_in[0];
    const float* targ = (const float*)d_in[1];
    const int*   mask = (const int*)d_in[2];
    const float* ptv  = (const float*)d_in[3];
    float* out = (float*)d_out;

    char* wsb = (char*)d_ws;
    int*   counter = (int*)wsb;                       // 1 int, zeroed per call
    float* wsd = (float*)(wsb + 256);                 // 3 * 4096 floats
    int*   wsc = (int*)(wsb + 256 + 3 * NBLOCKS * sizeof(float));

    hipMemsetAsync(counter, 0, sizeof(int), stream);

    dvh_kernel<<<NBLOCKS, BLOCK, 0, stream>>>(pred, targ, mask, ptv,
                                              wsd, wsc, counter, out);
}

// Round 9
// 41.690 us; speedup vs baseline: 11.7473x; 11.7473x over previous
//
#include <hip/hip_runtime.h>

// SigmoidDVHLoss: per-(batch,label) mean of sigmoid((dose-thr)/0.1) for pred
// and target, then MSE over the 8x3 DVH entries.
//
// loss = mean_{b,k} ( (sum_{m==k}(sig_p - sig_t)) / count_k )^2
//
// R5 (confirmed): global f64 hot-line atomics were the ~70us pacer ->
//   per-block partials + separate reduce = 41.5us.
// R6: staged vmcnt waits neutral -> steady state paced by shared XCD<->L3
//   stream rate (~5.4 TB/s effective); intra-wave scheduling irrelevant.
// R7 FAILED (490us): fused last-block epilogue -> per-block device-scope
//   __threadfence = L2 writeback per block on non-coherent XCD L2s. Never
//   fuse cross-XCD reductions without coherence-point stores.
// R8: revert to measured-best: single-wait 12-load asm block (R5) +
//   f32/i32 partials + two-kernel epilogue (R6).

#define NB 8
#define NK 3
#define VPB (1 << 21)        // 128^3 voxels per batch
#define BLOCK 256
#define CHUNKS 512           // blocks per batch
#define NBLOCKS (NB * CHUNKS)            // 4096
#define VOX_PER_BLOCK (VPB / CHUNKS)     // 4096 voxels = 1024 float4

#define LOG2E_X10 14.4269504088896341f   // 10 / ln(2)

typedef float v4f __attribute__((ext_vector_type(4)));
typedef int   v4i __attribute__((ext_vector_type(4)));

// ws layout: float diff[3][NBLOCKS] | int count[3][NBLOCKS]

__global__ __launch_bounds__(BLOCK) void dvh_sum_kernel(
    const float* __restrict__ pred,
    const float* __restrict__ targ,
    const int*   __restrict__ mask,
    const float* __restrict__ ptv,
    float*       __restrict__ wsd,
    int*         __restrict__ wsc)
{
    const int bid   = blockIdx.x;
    const int batch = bid / CHUNKS;
    const int chunk = bid % CHUNKS;
    const long base = (long)batch * VPB + (long)chunk * VOX_PER_BLOCK;

    const float* predb = pred + base;   // uniform -> SGPR pair
    const float* targb = targ + base;
    const int*   maskb = mask + base;

    const int tid = threadIdx.x;
    const unsigned off0 = (unsigned)(tid) * 16u;
    const unsigned off1 = (unsigned)(tid + BLOCK) * 16u;
    const unsigned off2 = (unsigned)(tid + 2 * BLOCK) * 16u;
    const unsigned off3 = (unsigned)(tid + 3 * BLOCK) * 16u;

    v4f P0, P1, P2, P3, T0, T1, T2, T3;
    v4i M0, M1, M2, M3;

    // all 12 loads issued back-to-back, one wait: 12 outstanding/thread
    asm volatile(
        "global_load_dwordx4 %0,  %12, %16\n\t"
        "global_load_dwordx4 %1,  %13, %16\n\t"
        "global_load_dwordx4 %2,  %14, %16\n\t"
        "global_load_dwordx4 %3,  %15, %16\n\t"
        "global_load_dwordx4 %4,  %12, %17\n\t"
        "global_load_dwordx4 %5,  %13, %17\n\t"
        "global_load_dwordx4 %6,  %14, %17\n\t"
        "global_load_dwordx4 %7,  %15, %17\n\t"
        "global_load_dwordx4 %8,  %12, %18\n\t"
        "global_load_dwordx4 %9,  %13, %18\n\t"
        "global_load_dwordx4 %10, %14, %18\n\t"
        "global_load_dwordx4 %11, %15, %18\n\t"
        "s_waitcnt vmcnt(0)"
        : "=&v"(P0), "=&v"(P1), "=&v"(P2), "=&v"(P3),
          "=&v"(T0), "=&v"(T1), "=&v"(T2), "=&v"(T3),
          "=&v"(M0), "=&v"(M1), "=&v"(M2), "=&v"(M3)
        : "v"(off0), "v"(off1), "v"(off2), "v"(off3),
          "s"(predb), "s"(targb), "s"(maskb));

    // scaled thresholds: sig = rcp(1 + 2^(thr*C - d*C))
    const float tc0 = ptv[0] * LOG2E_X10;
    const float tc1 = ptv[1] * LOG2E_X10;
    const float tc2 = ptv[2] * LOG2E_X10;

    float d0 = 0.f, d1 = 0.f, d2 = 0.f;   // sum of (sig_p - sig_t) per label
    int   c0 = 0,   c1 = 0,   c2 = 0;     // counts per label

    #define DO_ELEM(PJ, TJ, MJ)                                          \
    {                                                                    \
        const int mm = (MJ);                                             \
        const bool is1 = (mm == 1), is2 = (mm == 2), is3 = (mm == 3);    \
        const float thrC = is1 ? tc0 : (is2 ? tc1 : tc2);                \
        const float ep = __builtin_amdgcn_exp2f(                         \
                             __builtin_fmaf((PJ), -LOG2E_X10, thrC));    \
        const float et = __builtin_amdgcn_exp2f(                         \
                             __builtin_fmaf((TJ), -LOG2E_X10, thrC));    \
        const float sgp = __builtin_amdgcn_rcpf(1.0f + ep);              \
        const float sgt = __builtin_amdgcn_rcpf(1.0f + et);              \
        const float df  = sgp - sgt;                                     \
        d0 += is1 ? df : 0.0f;                                           \
        d1 += is2 ? df : 0.0f;                                           \
        d2 += is3 ? df : 0.0f;                                           \
        c0 += is1 ? 1 : 0;                                               \
        c1 += is2 ? 1 : 0;                                               \
        c2 += is3 ? 1 : 0;                                               \
    }

    #define DO_VEC4(P, T, M)                                             \
        DO_ELEM(P[0], T[0], M[0])                                        \
        DO_ELEM(P[1], T[1], M[1])                                        \
        DO_ELEM(P[2], T[2], M[2])                                        \
        DO_ELEM(P[3], T[3], M[3])

    DO_VEC4(P0, T0, M0)
    DO_VEC4(P1, T1, M1)
    DO_VEC4(P2, T2, M2)
    DO_VEC4(P3, T3, M3)
    #undef DO_VEC4
    #undef DO_ELEM

    // wave(64) butterfly reduce: f32 for diffs, int for counts
    #pragma unroll
    for (int off = 32; off > 0; off >>= 1) {
        d0 += __shfl_down(d0, off, 64);
        d1 += __shfl_down(d1, off, 64);
        d2 += __shfl_down(d2, off, 64);
        c0 += __shfl_down(c0, off, 64);
        c1 += __shfl_down(c1, off, 64);
        c2 += __shfl_down(c2, off, 64);
    }

    __shared__ float redd[BLOCK / 64][3];
    __shared__ int   redc[BLOCK / 64][3];
    const int wid  = threadIdx.x >> 6;
    const int lane = threadIdx.x & 63;
    if (lane == 0) {
        redd[wid][0] = d0; redd[wid][1] = d1; redd[wid][2] = d2;
        redc[wid][0] = c0; redc[wid][1] = c1; redc[wid][2] = c2;
    }
    __syncthreads();

    if (tid < 6) {
        const int q = tid;                   // 0..2 diff, 3..5 count
        if (q < 3)
            wsd[(size_t)q * NBLOCKS + bid] =
                redd[0][q] + redd[1][q] + redd[2][q] + redd[3][q];
        else
            wsc[(size_t)(q - 3) * NBLOCKS + bid] =
                redc[0][q - 3] + redc[1][q - 3] + redc[2][q - 3] + redc[3][q - 3];
    }
}

// Single block: reduce all 24 (b,k) pairs and emit the scalar loss.
__global__ __launch_bounds__(256) void dvh_finalize_kernel(
    const float* __restrict__ wsd,
    const int*   __restrict__ wsc,
    float*       __restrict__ out)
{
    const int tid  = threadIdx.x;
    const int wave = tid >> 6;
    const int lane = tid & 63;

    __shared__ double lds[NB * NK];

    for (int j = wave; j < NB * NK; j += 4) {        // 6 pairs per wave
        const int b = j / NK, k = j % NK;
        const float* dp = wsd + (size_t)k * NBLOCKS + b * CHUNKS;
        const int*   cp = wsc + (size_t)k * NBLOCKS + b * CHUNKS;

        double sd = 0.0;
        int    sc = 0;
        #pragma unroll
        for (int i = lane; i < CHUNKS; i += 64) {    // 8 elems each
            sd += (double)dp[i];
            sc += cp[i];
        }
        #pragma unroll
        for (int off = 32; off > 0; off >>= 1) {
            sd += __shfl_down(sd, off, 64);
            sc += __shfl_down(sc, off, 64);
        }
        if (lane == 0) {
            const double d = sd / (double)sc;
            lds[j] = d * d;
        }
    }
    __syncthreads();

    if (tid == 0) {
        double t = 0.0;
        #pragma unroll
        for (int j = 0; j < NB * NK; ++j) t += lds[j];
        out[0] = (float)(t / (double)(NB * NK));
    }
}

extern "C" void kernel_launch(void* const* d_in, const int* in_sizes, int n_in,
                              void* d_out, int out_size, void* d_ws, size_t ws_size,
                              hipStream_t stream) {
    const float* pred = (const float*)d_in[0];
    const float* targ = (const float*)d_in[1];
    const int*   mask = (const int*)d_in[2];
    const float* ptv  = (const float*)d_in[3];
    float* out = (float*)d_out;

    float* wsd = (float*)d_ws;                 // 3 * 4096 floats
    int*   wsc = (int*)(wsd + 3 * NBLOCKS);    // 3 * 4096 ints

    dvh_sum_kernel<<<NBLOCKS, BLOCK, 0, stream>>>(pred, targ, mask, ptv, wsd, wsc);
    dvh_finalize_kernel<<<1, 256, 0, stream>>>(wsd, wsc, out);
}